// Round 1
// 434.146 us; speedup vs baseline: 1.0978x; 1.0978x over previous
//
#include <hip/hip_runtime.h>
#include <hip/hip_bf16.h>

#define BB 32
#define TT 16
#define NNODE 512
#define CC 128

typedef __attribute__((ext_vector_type(8))) short bf16x8;
typedef __attribute__((ext_vector_type(4))) short short4_t;
typedef __attribute__((ext_vector_type(4))) float f32x4;

__device__ __forceinline__ short f2bf(float f) {
    __hip_bfloat16 h = __float2bfloat16(f);
    return *reinterpret_cast<short*>(&h);
}

#define GLD16(g, l)                                                          \
    __builtin_amdgcn_global_load_lds(                                        \
        (const __attribute__((address_space(1))) unsigned int*)(g),          \
        (__attribute__((address_space(3))) unsigned int*)(l), 16, 0, 0)

// ---------------------------------------------------------------------------
// Fused row-normalize prep: one wave per adj row.
// Abf[b][n][m] = bf16( (adj[n,m] + lamm1*delta_nm) / (sum_m adj[n,m] + lamm1) )
// ---------------------------------------------------------------------------
__global__ void prep_adj2_kernel(const float* __restrict__ adj,
                                 const float* __restrict__ lambdas, int layer,
                                 short* __restrict__ Abf) {
    int gid = blockIdx.x * blockDim.x + threadIdx.x;
    int row = gid >> 6;  // 0..16383 (b*512+n)
    int lane = gid & 63;
    int n = row & (NNODE - 1);
    const float* r = adj + (long)row * NNODE;
    float4 f0 = *(const float4*)(r + lane * 4);
    float4 f1 = *(const float4*)(r + 256 + lane * 4);
    float s = f0.x + f0.y + f0.z + f0.w + f1.x + f1.y + f1.z + f1.w;
#pragma unroll
    for (int o = 32; o; o >>= 1) s += __shfl_xor(s, o, 64);
    float lamm1 = fmaxf(lambdas[layer], 0.f);
    float inv = 1.f / (s + lamm1);
    float v[8] = {f0.x, f0.y, f0.z, f0.w, f1.x, f1.y, f1.z, f1.w};
#pragma unroll
    for (int j = 0; j < 8; ++j) v[j] *= inv;
    int d0 = n - lane * 4;
    if (d0 >= 0 && d0 < 4) v[d0] += lamm1 * inv;
    int d1 = n - 256 - lane * 4;
    if (d1 >= 0 && d1 < 4) v[4 + d1] += lamm1 * inv;
    short* o = Abf + (long)row * NNODE;
    short4_t s0 = {f2bf(v[0]), f2bf(v[1]), f2bf(v[2]), f2bf(v[3])};
    short4_t s1 = {f2bf(v[4]), f2bf(v[5]), f2bf(v[6]), f2bf(v[7])};
    *(short4_t*)(o + lane * 4) = s0;
    *(short4_t*)(o + 256 + lane * 4) = s1;
}

// thT[i][k] = bf16(theta[k][i])   (B-operand wants [n=c_out][k=c_in] rows)
__global__ void prep_theta_kernel(const float* __restrict__ theta,
                                  short* __restrict__ thT) {
    int idx = blockIdx.x * 256 + threadIdx.x;
    int i = idx >> 7, k = idx & (CC - 1);
    thT[i * CC + k] = f2bf(theta[k * CC + i]);
}

// ---------------------------------------------------------------------------
// theta GEMM (layer 0): D[m][c] = X[m][k] @ theta[k][c], stored TRANSPOSED
// as Ht[bt][c][m_local] (bf16). X fp32, converted to bf16 during A-staging.
// ---------------------------------------------------------------------------
__global__ __launch_bounds__(256) void gemm_theta_mfma(
    const float* __restrict__ X, const short* __restrict__ thT,
    short* __restrict__ Ht) {
    __shared__ short As[128 * 32];  // [m_local][k]
    __shared__ short Bs[128 * 32];  // [c_out][k]
    const int t = threadIdx.x;
    const long rowBase = (long)blockIdx.x * 128;
    const int w = t >> 6, ln = t & 63;
    const int lm = ln & 15, q = ln >> 4;
    const int wy = w >> 1, wx = w & 1;

    f32x4 acc[4][4] = {};

    const int rr = w * 32 + (ln >> 2);
    const int kc = (ln & 3) * 8;
    short* ldsB = Bs + w * 1024 + ln * 8;

    for (int k0 = 0; k0 < CC; k0 += 32) {
        __syncthreads();
        const short* gb = thT + rr * CC + k0 + kc;
        GLD16(gb, ldsB);
        GLD16(gb + 16 * CC, ldsB + 512);
#pragma unroll
        for (int i = 0; i < 4; ++i) {
            int v = i * 256 + t;  // float4 index in 128x32 tile
            int r = v >> 3, kq = v & 7;
            float4 f = *(const float4*)(X + (rowBase + r) * CC + k0 + kq * 4);
            short4_t s = {f2bf(f.x), f2bf(f.y), f2bf(f.z), f2bf(f.w)};
            *(short4_t*)(&As[r * 32 + kq * 4]) = s;
        }
        __syncthreads();

        bf16x8 a[4], b[4];
#pragma unroll
        for (int i = 0; i < 4; ++i)
            a[i] = *(const bf16x8*)(&As[(wy * 64 + i * 16 + lm) * 32 + q * 8]);
#pragma unroll
        for (int j = 0; j < 4; ++j)
            b[j] = *(const bf16x8*)(&Bs[(wx * 64 + j * 16 + lm) * 32 + q * 8]);
#pragma unroll
        for (int i = 0; i < 4; ++i)
#pragma unroll
            for (int j = 0; j < 4; ++j)
                acc[i][j] = __builtin_amdgcn_mfma_f32_16x16x32_bf16(
                    a[i], b[j], acc[i][j], 0, 0, 0);
    }

    const long bt = rowBase >> 9;
    const int mBase = (int)(rowBase & (NNODE - 1));
    short* Hb = Ht + bt * (long)(NNODE * CC);
#pragma unroll
    for (int i = 0; i < 4; ++i) {
        int m = mBase + wy * 64 + i * 16 + q * 4;
#pragma unroll
        for (int j = 0; j < 4; ++j) {
            int c = wx * 64 + j * 16 + lm;
            f32x4 v = acc[i][j];
            short4_t s = {f2bf(v[0]), f2bf(v[1]), f2bf(v[2]), f2bf(v[3])};
            *(short4_t*)(&Hb[(long)c * NNODE + m]) = s;
        }
    }
}

// ---------------------------------------------------------------------------
// FUSED agg(layer0) + theta(layer1):
//   tile = relu( Abf0[b][n0:n0+128][:] @ Ht1[bt][:][:] )   (K = 512)
//   Ht2[bt][cout][n0:n0+128] = tile[m][:] . thT2[cout][:]  (K = C = 128)
// Each block owns all 128 c-columns, so the theta-1 contraction is fully
// block-local: relu'd tile -> LDS (bf16, padded), 4-step second GEMM.
// ---------------------------------------------------------------------------
__global__ __launch_bounds__(256) void gemm_agg_theta(
    const short* __restrict__ Abf, const short* __restrict__ Ht1,
    const short* __restrict__ thT2, short* __restrict__ Ht2) {
    __shared__ short As[128 * 32];   // [n_local][k=m]
    __shared__ short Bs[128 * 32];   // [c][k=m]  (reused for thT2 tiles)
    __shared__ short Ts[128][136];   // relu'd tile [m_local][c], +8 pad
    const int t = threadIdx.x;
    const int bt = blockIdx.y;
    const int n0 = blockIdx.x * 128;
    const short* Ab = Abf + (long)(bt >> 4) * NNODE * NNODE + (long)n0 * NNODE;
    const short* Hb = Ht1 + (long)bt * NNODE * CC;
    const int w = t >> 6, ln = t & 63;
    const int lm = ln & 15, q = ln >> 4;
    const int wy = w >> 1, wx = w & 1;

    f32x4 acc[4][4] = {};

    const int rr = w * 32 + (ln >> 2);
    const int kc = (ln & 3) * 8;
    short* ldsA = As + w * 1024 + ln * 8;
    short* ldsB = Bs + w * 1024 + ln * 8;

    for (int k0 = 0; k0 < NNODE; k0 += 32) {
        __syncthreads();
        const short* ga = Ab + (long)rr * NNODE + k0 + kc;
        const short* gb = Hb + (long)rr * NNODE + k0 + kc;
        GLD16(ga, ldsA);
        GLD16(ga + 16 * NNODE, ldsA + 512);
        GLD16(gb, ldsB);
        GLD16(gb + 16 * NNODE, ldsB + 512);
        __syncthreads();

        bf16x8 a[4], b[4];
#pragma unroll
        for (int i = 0; i < 4; ++i)
            a[i] = *(const bf16x8*)(&As[(wy * 64 + i * 16 + lm) * 32 + q * 8]);
#pragma unroll
        for (int j = 0; j < 4; ++j)
            b[j] = *(const bf16x8*)(&Bs[(wx * 64 + j * 16 + lm) * 32 + q * 8]);
#pragma unroll
        for (int i = 0; i < 4; ++i)
#pragma unroll
            for (int j = 0; j < 4; ++j)
                acc[i][j] = __builtin_amdgcn_mfma_f32_16x16x32_bf16(
                    a[i], b[j], acc[i][j], 0, 0, 0);
    }

    // relu + bf16-round the tile into Ts[m_local][c] (k-contiguous rows for
    // the second GEMM's A fragments). Same rounding point as the old
    // pipeline (theta-1 A-staging did bf16(relu(hid))) -> bit-identical.
#pragma unroll
    for (int i = 0; i < 4; ++i)
#pragma unroll
        for (int j = 0; j < 4; ++j)
#pragma unroll
            for (int r = 0; r < 4; ++r)
                Ts[wy * 64 + i * 16 + q * 4 + r][wx * 64 + j * 16 + lm] =
                    f2bf(fmaxf(acc[i][j][r], 0.f));

    // second GEMM: K = C = 128, 4 steps; thT2 tiles staged into Bs via GLD16
    f32x4 acc2[4][4] = {};
    for (int c0 = 0; c0 < CC; c0 += 32) {
        __syncthreads();  // also covers Ts-writes -> Ts-reads (first iter)
        const short* gb = thT2 + rr * CC + c0 + kc;
        GLD16(gb, ldsB);
        GLD16(gb + 16 * CC, ldsB + 512);
        __syncthreads();

        bf16x8 a[4], b[4];
#pragma unroll
        for (int i = 0; i < 4; ++i)
            a[i] = *(const bf16x8*)(&Ts[wy * 64 + i * 16 + lm][c0 + q * 8]);
#pragma unroll
        for (int j = 0; j < 4; ++j)
            b[j] = *(const bf16x8*)(&Bs[(wx * 64 + j * 16 + lm) * 32 + q * 8]);
#pragma unroll
        for (int i = 0; i < 4; ++i)
#pragma unroll
            for (int j = 0; j < 4; ++j)
                acc2[i][j] = __builtin_amdgcn_mfma_f32_16x16x32_bf16(
                    a[i], b[j], acc2[i][j], 0, 0, 0);
    }

    // store transposed: Ht2[bt][cout][m], lane's 4 regs are consecutive m
    short* Hb2 = Ht2 + (long)bt * NNODE * CC;
#pragma unroll
    for (int i = 0; i < 4; ++i) {
        int m = n0 + wy * 64 + i * 16 + q * 4;
#pragma unroll
        for (int j = 0; j < 4; ++j) {
            int c = wx * 64 + j * 16 + lm;
            f32x4 v = acc2[i][j];
            short4_t sv = {f2bf(v[0]), f2bf(v[1]), f2bf(v[2]), f2bf(v[3])};
            *(short4_t*)(&Hb2[(long)c * NNODE + m]) = sv;
        }
    }
}

// ---------------------------------------------------------------------------
// final agg GEMM: out[bt][n][c] = relu(x) + sigmoid(relu(Abf1 @ Ht2)), K=512
// ---------------------------------------------------------------------------
template <int FUSE>
__global__ __launch_bounds__(256) void gemm_agg_mfma(
    const short* __restrict__ Abf, const short* __restrict__ Ht,
    const float* __restrict__ x, float* __restrict__ Out) {
    __shared__ short As[128 * 32];  // [n_local][k=m]
    __shared__ short Bs[128 * 32];  // [c][k=m]
    const int t = threadIdx.x;
    const int bt = blockIdx.y;
    const int n0 = blockIdx.x * 128;
    const short* Ab = Abf + (long)(bt >> 4) * NNODE * NNODE + (long)n0 * NNODE;
    const short* Hb = Ht + (long)bt * NNODE * CC;
    const int w = t >> 6, ln = t & 63;
    const int lm = ln & 15, q = ln >> 4;
    const int wy = w >> 1, wx = w & 1;

    f32x4 acc[4][4] = {};

    const int rr = w * 32 + (ln >> 2);
    const int kc = (ln & 3) * 8;
    short* ldsA = As + w * 1024 + ln * 8;
    short* ldsB = Bs + w * 1024 + ln * 8;

    for (int k0 = 0; k0 < NNODE; k0 += 32) {
        __syncthreads();
        const short* ga = Ab + (long)rr * NNODE + k0 + kc;
        const short* gb = Hb + (long)rr * NNODE + k0 + kc;
        GLD16(ga, ldsA);
        GLD16(ga + 16 * NNODE, ldsA + 512);
        GLD16(gb, ldsB);
        GLD16(gb + 16 * NNODE, ldsB + 512);
        __syncthreads();

        bf16x8 a[4], b[4];
#pragma unroll
        for (int i = 0; i < 4; ++i)
            a[i] = *(const bf16x8*)(&As[(wy * 64 + i * 16 + lm) * 32 + q * 8]);
#pragma unroll
        for (int j = 0; j < 4; ++j)
            b[j] = *(const bf16x8*)(&Bs[(wx * 64 + j * 16 + lm) * 32 + q * 8]);
#pragma unroll
        for (int i = 0; i < 4; ++i)
#pragma unroll
            for (int j = 0; j < 4; ++j)
                acc[i][j] = __builtin_amdgcn_mfma_f32_16x16x32_bf16(
                    a[i], b[j], acc[i][j], 0, 0, 0);
    }

    const long obase = (long)bt * NNODE * CC;
#pragma unroll
    for (int i = 0; i < 4; ++i) {
        int n = n0 + wy * 64 + i * 16 + q * 4;
#pragma unroll
        for (int j = 0; j < 4; ++j) {
            int c = wx * 64 + j * 16 + lm;
#pragma unroll
            for (int r = 0; r < 4; ++r) {
                long idx = obase + (long)(n + r) * CC + c;
                float v = fmaxf(acc[i][j][r], 0.f);
                if (FUSE) {
                    Out[idx] = fmaxf(x[idx], 0.f) + 1.f / (1.f + __expf(-v));
                } else {
                    Out[idx] = v;
                }
            }
        }
    }
}

extern "C" void kernel_launch(void* const* d_in, const int* in_sizes, int n_in,
                              void* d_out, int out_size, void* d_ws,
                              size_t ws_size, hipStream_t stream) {
    const float* x = (const float*)d_in[0];
    const float* adj = (const float*)d_in[1];
    const float* lambdas = (const float*)d_in[2];
    const float* thetas = (const float*)d_in[3];
    float* out = (float*)d_out;

    // workspace: Abf (16.78 MB, reused across layers) + Ht2 (67.1 MB)
    //            + 2 transposed thetas (64 KB)  -> ~84 MB (same as before)
    short* Abf = (short*)d_ws;
    short* Ht2 = Abf + (long)BB * NNODE * NNODE;
    short* thT0 = Ht2 + (long)BB * TT * NNODE * CC;
    short* thT1 = thT0 + CC * CC;
    // Ht1 (67.1 MB bf16) lives in the out buffer (134 MB fp32): it is dead
    // before the final agg GEMM overwrites this memory with fp32 output.
    short* Ht1 = (short*)out;

    dim3 blk(256);
    dim3 g_agg(NNODE / 128, BB * TT);

    prep_adj2_kernel<<<4096, blk, 0, stream>>>(adj, lambdas, 0, Abf);
    prep_theta_kernel<<<64, blk, 0, stream>>>(thetas, thT0);
    prep_theta_kernel<<<64, blk, 0, stream>>>(thetas + CC * CC, thT1);

    // layer 0 theta: x @ theta0 -> Ht1 (transposed bf16, in out buffer)
    gemm_theta_mfma<<<2048, blk, 0, stream>>>(x, thT0, Ht1);

    // fused: agg layer 0 + theta layer 1 -> Ht2 (no fp32 hid roundtrip)
    gemm_agg_theta<<<g_agg, blk, 0, stream>>>(Abf, Ht1, thT1, Ht2);

    // layer 1 aggregation + final epilogue
    prep_adj2_kernel<<<4096, blk, 0, stream>>>(adj, lambdas, 1, Abf);
    gemm_agg_mfma<1><<<g_agg, blk, 0, stream>>>(Abf, Ht2, x, out);
}